// Round 2
// 166.202 us; speedup vs baseline: 1.0214x; 1.0214x over previous
//
#include <hip/hip_runtime.h>

// RoPE: out[b,s,2j]   = cos(a)*x[b,s,2j] - sin(a)*x[b,s,2j+1]
//       out[b,s,2j+1] = sin(a)*x[b,s,2j] + cos(a)*x[b,s,2j+1]
// a = pos * theta^(-j/32), pos = token_positions[b,s], j in [0,32)
//
// R5 = R4 with the nontemporal type fix: __builtin_nontemporal_load/store
// reject HIP's float4 (a class); use clang ext_vector_type(4) float, which
// is a true vector type and is accepted.
//
// R4 changes (kept):
//  - 2 float4 per lane (32B contiguous): 4096 waves instead of 8192,
//    two independent loads in flight per lane, half the tp/addr overhead.
//  - single v_exp_f32 per lane: the 4 consecutive j values share
//    rev(j+k) = rev(j) * theta^(-k/32); r1..r3 via constant v_mul.
//    Added rel error ~1e-7 * 1304rev ~ 1.3e-4 rev ~ 8e-4 rad << 0.102 thr.
//  - nontemporal load/store on the streaming x/out traffic (each line
//    touched exactly once; poison fills flush LLC between iterations
//    anyway). tp stays cached (reused by 8 lanes per row).
//
// NOTE: dur_us has a ~158us floor from the harness's two 536MB d_ws poison
// fills (fillBufferAligned @ ~79us each in rocprof); our kernel is the
// remaining ~11us slice. This round targets that slice; if dur_us is
// unchanged the slice is graph-launch overhead and we are at the floor.

#define DK4 16  // float4 chunks per d_k row

typedef float f4 __attribute__((ext_vector_type(4)));

__global__ __launch_bounds__(256) void rope_kernel(
    const float* __restrict__ x,
    const int* __restrict__ tp,
    float* __restrict__ out,
    int n8)  // total 8-float chunks (= n/8)
{
    int t = blockIdx.x * blockDim.x + threadIdx.x;
    if (t >= n8) return;

    int i0    = t << 1;            // first float4 index (even)
    int quad0 = i0 & (DK4 - 1);    // even quad within the 64-elem row
    int p     = i0 >> 4;           // flat (b,s) index

    int pos = tp[p];               // cached; 8 lanes/row share this

    const f4* __restrict__ x4 = (const f4*)x;
    f4 va = __builtin_nontemporal_load(&x4[i0]);
    f4 vb = __builtin_nontemporal_load(&x4[i0 + 1]);

    const float L  = 0.41524101186092028f;  // log2(10000)/32
    const float C  = 2.6514961294723187f;   // log2(2*pi)
    const float K1 = 0.74989420933245585f;  // 10000^(-1/32)
    const float K2 = 0.56234132519034907f;  // 10000^(-2/32)
    const float K3 = 0.42169650342858224f;  // 10000^(-3/32)

    float fpos = (float)pos;
    float j0   = (float)(quad0 << 1);

    // revolutions = pos * theta^(-j/32) / (2*pi); one exp2, rest derived
    float r0 = fpos * __builtin_amdgcn_exp2f(__builtin_fmaf(-j0, L, -C));
    float r1 = r0 * K1;
    float r2 = r0 * K2;
    float r3 = r0 * K3;
    r0 -= floorf(r0);   // v_fract_f32
    r1 -= floorf(r1);
    r2 -= floorf(r2);
    r3 -= floorf(r3);

    float s0 = __builtin_amdgcn_sinf(r0);  // sin(2*pi*r)
    float c0 = __builtin_amdgcn_cosf(r0);
    float s1 = __builtin_amdgcn_sinf(r1);
    float c1 = __builtin_amdgcn_cosf(r1);
    float s2 = __builtin_amdgcn_sinf(r2);
    float c2 = __builtin_amdgcn_cosf(r2);
    float s3 = __builtin_amdgcn_sinf(r3);
    float c3 = __builtin_amdgcn_cosf(r3);

    f4 ra, rb;
    ra.x = c0 * va.x - s0 * va.y;
    ra.y = s0 * va.x + c0 * va.y;
    ra.z = c1 * va.z - s1 * va.w;
    ra.w = s1 * va.z + c1 * va.w;
    rb.x = c2 * vb.x - s2 * vb.y;
    rb.y = s2 * vb.x + c2 * vb.y;
    rb.z = c3 * vb.z - s3 * vb.w;
    rb.w = s3 * vb.z + c3 * vb.w;

    f4* __restrict__ o4 = (f4*)out;
    __builtin_nontemporal_store(ra, &o4[i0]);
    __builtin_nontemporal_store(rb, &o4[i0 + 1]);
}

extern "C" void kernel_launch(void* const* d_in, const int* in_sizes, int n_in,
                              void* d_out, int out_size, void* d_ws, size_t ws_size,
                              hipStream_t stream) {
    const float* x  = (const float*)d_in[0];   // (4, 8192, 64) fp32
    const int*   tp = (const int*)d_in[1];     // (4, 8192) int32
    // d_in[2] = rope_buffer (8192,64,64) fp32 -- intentionally unused.
    float* out = (float*)d_out;

    int n  = in_sizes[0];      // 2097152 floats
    int n8 = n / 8;            // 262144 8-float chunks
    int block = 256;
    int grid = (n8 + block - 1) / block;   // 1024
    rope_kernel<<<grid, block, 0, stream>>>(x, tp, out, n8);
}